// Round 1
// baseline (1296.739 us; speedup 1.0000x reference)
//
#include <hip/hip_runtime.h>

#define EDIM 1024
#define HNUM 16
#define HD   64
#define BB   2
#define SS   2048
#define MTOT (BB * SS)

// ---------------------------------------------------------------------------
// Tiled fp32 GEMM: O[m][n] = sum_k A[m][k] * W[k][wcol0+n] + bias[wcol0+n]
// A: [MTOT][EDIM], W: [EDIM][ldw], O: [MTOT][EDIM-wide rows, N=1024]
// 64x64 tile, BK=16, 256 threads, 4x4 micro-tile, register prefetch.
// ---------------------------------------------------------------------------
__global__ __launch_bounds__(256) void gemm_proj(
    const float* __restrict__ A, const float* __restrict__ W,
    const float* __restrict__ bias, float* __restrict__ O,
    int ldw, int wcol0)
{
  __shared__ float Asl[16][64];  // transposed A tile: [k][m]
  __shared__ float Bsl[16][64];  // [k][n]

  const int tid = threadIdx.x;
  const int tx = tid & 15, ty = tid >> 4;
  const int m0 = blockIdx.x * 64;
  const int n0 = blockIdx.y * 64;

  const int arow = tid >> 2, acol = (tid & 3) * 4;   // A tile: 64 rows x 16 k
  const int brow = tid >> 4, bcol = (tid & 15) * 4;  // B tile: 16 k x 64 n

  const float* aptr = A + (size_t)(m0 + arow) * EDIM + acol;
  const float* bptr = W + (size_t)brow * ldw + wcol0 + n0 + bcol;

  float4 a4 = *reinterpret_cast<const float4*>(aptr);
  float4 b4 = *reinterpret_cast<const float4*>(bptr);

  float acc[4][4] = {};

  for (int k0 = 0; k0 < EDIM; k0 += 16) {
    Asl[acol + 0][arow] = a4.x;
    Asl[acol + 1][arow] = a4.y;
    Asl[acol + 2][arow] = a4.z;
    Asl[acol + 3][arow] = a4.w;
    *reinterpret_cast<float4*>(&Bsl[brow][bcol]) = b4;
    __syncthreads();

    if (k0 + 16 < EDIM) {  // register prefetch of next k-tile
      a4 = *reinterpret_cast<const float4*>(aptr + k0 + 16);
      b4 = *reinterpret_cast<const float4*>(bptr + (size_t)(k0 + 16) * ldw);
    }

    #pragma unroll
    for (int k = 0; k < 16; ++k) {
      const float4 av = *reinterpret_cast<const float4*>(&Asl[k][ty * 4]);
      const float4 bv = *reinterpret_cast<const float4*>(&Bsl[k][tx * 4]);
      const float ar[4] = {av.x, av.y, av.z, av.w};
      const float br[4] = {bv.x, bv.y, bv.z, bv.w};
      #pragma unroll
      for (int i = 0; i < 4; ++i)
        #pragma unroll
        for (int j = 0; j < 4; ++j)
          acc[i][j] = fmaf(ar[i], br[j], acc[i][j]);
    }
    __syncthreads();
  }

  const float4 bb4 = *reinterpret_cast<const float4*>(bias + wcol0 + n0 + tx * 4);
  #pragma unroll
  for (int i = 0; i < 4; ++i) {
    const int m = m0 + ty * 4 + i;
    float4 o;
    o.x = acc[i][0] + bb4.x;
    o.y = acc[i][1] + bb4.y;
    o.z = acc[i][2] + bb4.z;
    o.w = acc[i][3] + bb4.w;
    *reinterpret_cast<float4*>(O + (size_t)m * EDIM + n0 + tx * 4) = o;
  }
}

// ---------------------------------------------------------------------------
// Flash-style attention, fp32. One block per (b, h, 64-row q tile).
// K-tile = 64 keys. Online softmax with running (m, l) per q-row.
// P is staged through the (dead after QK^T) K LDS buffer -> 50.4 KB LDS.
// ---------------------------------------------------------------------------
__global__ __launch_bounds__(256) void attn_fused(
    const float* __restrict__ Qp, const float* __restrict__ Kp,
    const float* __restrict__ Vp, const int* __restrict__ mask,
    float* __restrict__ Ctx)
{
  __shared__ float Qs[64][64];  // [d][qrow], pre-scaled by 1/sqrt(D)
  __shared__ float KP[64][68];  // K phase: [d][key]; P phase: [key][qrow] (padded)
  __shared__ float Vs[64][64];  // [key][d]

  const int tid = threadIdx.x;
  const int tx = tid & 15, ty = tid >> 4;
  const int q0 = blockIdx.x * 64;
  const int h  = blockIdx.y;
  const int b  = blockIdx.z;

  const size_t hbase = (size_t)b * SS * EDIM + (size_t)h * HD;

  const int lr = tid >> 2;        // 0..63: tile row this thread stages
  const int lc = (tid & 3) * 16;  // 0/16/32/48: starting col group

  // ---- load Q tile (transposed into [d][row], pre-scaled) ----
  #pragma unroll
  for (int l = 0; l < 4; ++l) {
    const float4 f = *reinterpret_cast<const float4*>(
        Qp + hbase + (size_t)(q0 + lr) * EDIM + lc + l * 4);
    Qs[lc + l * 4 + 0][lr] = f.x * 0.125f;
    Qs[lc + l * 4 + 1][lr] = f.y * 0.125f;
    Qs[lc + l * 4 + 2][lr] = f.z * 0.125f;
    Qs[lc + l * 4 + 3][lr] = f.w * 0.125f;
  }

  float acc[4][4] = {};
  float mrow[4] = {-1e30f, -1e30f, -1e30f, -1e30f};
  float lrow[4] = {};

  // prefetch first K/V tile into registers
  float4 kf[4], vf[4];
  #pragma unroll
  for (int l = 0; l < 4; ++l) {
    kf[l] = *reinterpret_cast<const float4*>(Kp + hbase + (size_t)lr * EDIM + lc + l * 4);
    vf[l] = *reinterpret_cast<const float4*>(Vp + hbase + (size_t)lr * EDIM + lc + l * 4);
  }

  for (int t = 0; t < SS / 64; ++t) {
    // ---- stage K (transposed) and V (natural) from prefetch regs ----
    #pragma unroll
    for (int l = 0; l < 4; ++l) {
      KP[lc + l * 4 + 0][lr] = kf[l].x;
      KP[lc + l * 4 + 1][lr] = kf[l].y;
      KP[lc + l * 4 + 2][lr] = kf[l].z;
      KP[lc + l * 4 + 3][lr] = kf[l].w;
      *reinterpret_cast<float4*>(&Vs[lr][lc + l * 4]) = vf[l];
    }
    __syncthreads();  // sync1: tiles visible

    if (t + 1 < SS / 64) {  // prefetch next tile (latency hidden under QK^T)
      const size_t nb = hbase + (size_t)((t + 1) * 64 + lr) * EDIM + lc;
      #pragma unroll
      for (int l = 0; l < 4; ++l) {
        kf[l] = *reinterpret_cast<const float4*>(Kp + nb + l * 4);
        vf[l] = *reinterpret_cast<const float4*>(Vp + nb + l * 4);
      }
    }

    // ---- S = (Q/8) K^T : 64x64, each thread 4x4 ----
    float sv[4][4] = {};
    #pragma unroll 16
    for (int d = 0; d < 64; ++d) {
      const float4 qa = *reinterpret_cast<const float4*>(&Qs[d][ty * 4]);
      const float4 kb = *reinterpret_cast<const float4*>(&KP[d][tx * 4]);
      const float qr[4] = {qa.x, qa.y, qa.z, qa.w};
      const float kr[4] = {kb.x, kb.y, kb.z, kb.w};
      #pragma unroll
      for (int i = 0; i < 4; ++i)
        #pragma unroll
        for (int j = 0; j < 4; ++j)
          sv[i][j] = fmaf(qr[i], kr[j], sv[i][j]);
    }

    // ---- mask ----
    const int k0 = t * 64;
    #pragma unroll
    for (int i = 0; i < 4; ++i) {
      const int4 mm = *reinterpret_cast<const int4*>(
          mask + (size_t)(q0 + ty * 4 + i) * SS + k0 + tx * 4);
      if (mm.x == 0) sv[i][0] = -1e30f;
      if (mm.y == 0) sv[i][1] = -1e30f;
      if (mm.z == 0) sv[i][2] = -1e30f;
      if (mm.w == 0) sv[i][3] = -1e30f;
    }

    // ---- online softmax: row max over the 16 lanes sharing each q-row ----
    float pm[4];
    #pragma unroll
    for (int i = 0; i < 4; ++i)
      pm[i] = fmaxf(fmaxf(sv[i][0], sv[i][1]), fmaxf(sv[i][2], sv[i][3]));
    #pragma unroll
    for (int off = 1; off < 16; off <<= 1)
      #pragma unroll
      for (int i = 0; i < 4; ++i)
        pm[i] = fmaxf(pm[i], __shfl_xor(pm[i], off, 64));

    float scl[4], ls[4] = {};
    #pragma unroll
    for (int i = 0; i < 4; ++i) {
      const float mn = fmaxf(mrow[i], pm[i]);
      scl[i] = __expf(mrow[i] - mn);
      mrow[i] = mn;
    }
    #pragma unroll
    for (int i = 0; i < 4; ++i)
      #pragma unroll
      for (int j = 0; j < 4; ++j) {
        // guard: fully-masked tile row must contribute exactly 0
        const float p = (sv[i][j] <= -1e29f) ? 0.f : __expf(sv[i][j] - mrow[i]);
        sv[i][j] = p;
        ls[i] += p;
      }
    #pragma unroll
    for (int off = 1; off < 16; off <<= 1)
      #pragma unroll
      for (int i = 0; i < 4; ++i)
        ls[i] += __shfl_xor(ls[i], off, 64);
    #pragma unroll
    for (int i = 0; i < 4; ++i) {
      lrow[i] = lrow[i] * scl[i] + ls[i];
      #pragma unroll
      for (int j = 0; j < 4; ++j) acc[i][j] *= scl[i];
    }

    __syncthreads();  // sync2: everyone done reading K region of KP

    // ---- write P transposed into KP: KP[key][qrow] ----
    #pragma unroll
    for (int i = 0; i < 4; ++i)
      #pragma unroll
      for (int j = 0; j < 4; ++j)
        KP[tx * 4 + j][ty * 4 + i] = sv[i][j];
    __syncthreads();  // sync3: P visible

    // ---- acc += P V : each thread 4 qrows x 4 dims ----
    #pragma unroll 16
    for (int j = 0; j < 64; ++j) {
      const float4 pa = *reinterpret_cast<const float4*>(&KP[j][ty * 4]);
      const float4 vb = *reinterpret_cast<const float4*>(&Vs[j][tx * 4]);
      const float pr[4] = {pa.x, pa.y, pa.z, pa.w};
      const float vr[4] = {vb.x, vb.y, vb.z, vb.w};
      #pragma unroll
      for (int i = 0; i < 4; ++i)
        #pragma unroll
        for (int c = 0; c < 4; ++c)
          acc[i][c] = fmaf(pr[i], vr[c], acc[i][c]);
    }
    __syncthreads();  // sync4: done reading KP/Vs before next stage
  }

  // ---- epilogue: ctx = acc / l ----
  #pragma unroll
  for (int i = 0; i < 4; ++i) {
    const float inv = 1.0f / lrow[i];
    float4 o;
    o.x = acc[i][0] * inv;
    o.y = acc[i][1] * inv;
    o.z = acc[i][2] * inv;
    o.w = acc[i][3] * inv;
    *reinterpret_cast<float4*>(
        Ctx + hbase + (size_t)(q0 + ty * 4 + i) * EDIM + tx * 4) = o;
  }
}

// ---------------------------------------------------------------------------
extern "C" void kernel_launch(void* const* d_in, const int* in_sizes, int n_in,
                              void* d_out, int out_size, void* d_ws, size_t ws_size,
                              hipStream_t stream) {
  const float* q    = (const float*)d_in[0];
  const float* k    = (const float*)d_in[1];
  const float* v    = (const float*)d_in[2];
  const int*   mask = (const int*)d_in[3];
  const float* Wqkv = (const float*)d_in[4];
  const float* bqkv = (const float*)d_in[5];
  const float* Wout = (const float*)d_in[6];
  const float* bout = (const float*)d_in[7];
  float* out = (float*)d_out;

  const size_t mat = (size_t)MTOT * EDIM;
  float* Qp  = (float*)d_ws;
  float* Kp  = Qp + mat;
  float* Vp  = Kp + mat;
  float* Ctx = Vp + mat;

  const dim3 gg(MTOT / 64, EDIM / 64);
  // Only the used E-slice of each projection is computed.
  gemm_proj<<<gg, 256, 0, stream>>>(q, Wqkv, bqkv, Qp, 3 * EDIM, 0);
  gemm_proj<<<gg, 256, 0, stream>>>(k, Wqkv, bqkv, Kp, 3 * EDIM, EDIM);
  gemm_proj<<<gg, 256, 0, stream>>>(v, Wqkv, bqkv, Vp, 3 * EDIM, 2 * EDIM);

  attn_fused<<<dim3(SS / 64, HNUM, BB), 256, 0, stream>>>(Qp, Kp, Vp, mask, Ctx);

  gemm_proj<<<gg, 256, 0, stream>>>(Ctx, Wout, bout, out, EDIM, 0);
}

// Round 2
// 387.740 us; speedup vs baseline: 3.3443x; 3.3443x over previous
//
#include <hip/hip_runtime.h>
#include <stdint.h>

#define EDIM 1024
#define HNUM 16
#define HD   64
#define BB   2
#define SS   2048
#define MTOT (BB * SS)

typedef __attribute__((ext_vector_type(8))) __bf16 bf16x8;
typedef __attribute__((ext_vector_type(8))) short short8;
typedef __attribute__((ext_vector_type(4))) float f32x4;

__device__ __forceinline__ short f2bf(float f) {
  union { float f; unsigned u; } x{f};
  unsigned r = (x.u + 0x7FFFu + ((x.u >> 16) & 1u)) >> 16;
  return (short)r;
}

__device__ __forceinline__ void gload16(const void* g, void* l) {
  __builtin_amdgcn_global_load_lds((const __attribute__((address_space(1))) void*)g,
                                   (__attribute__((address_space(3))) void*)l, 16, 0, 0);
}

// ---------------------------------------------------------------------------
// f32 -> bf16 cast, 8 elements/thread
// ---------------------------------------------------------------------------
__global__ __launch_bounds__(256) void cast_bf16(const float* __restrict__ s,
                                                 short* __restrict__ d, int n8) {
  int i = blockIdx.x * 256 + threadIdx.x;
  if (i >= n8) return;
  const float4* sp = (const float4*)s + (size_t)i * 2;
  float4 a = sp[0], b = sp[1];
  short8 r;
  r[0] = f2bf(a.x); r[1] = f2bf(a.y); r[2] = f2bf(a.z); r[3] = f2bf(a.w);
  r[4] = f2bf(b.x); r[5] = f2bf(b.y); r[6] = f2bf(b.z); r[7] = f2bf(b.w);
  *(short8*)(d + (size_t)i * 8) = r;
}

// ---------------------------------------------------------------------------
// Transpose+cast: D[n][k] = bf16(W[k][col0+n]), D is [1024][1024]
// ---------------------------------------------------------------------------
__global__ __launch_bounds__(256) void tcast(const float* __restrict__ W, int ld,
                                             int col0, short* __restrict__ D) {
  __shared__ short L[64][80];  // padded rows (160B, 16B-aligned)
  const int t = threadIdx.x;
  const int k0 = blockIdx.x * 64, n0 = blockIdx.y * 64;
  {
    const int kr = t >> 2, nc0 = (t & 3) * 16;
    #pragma unroll
    for (int u = 0; u < 4; ++u) {
      float4 f = *(const float4*)(W + (size_t)(k0 + kr) * ld + col0 + n0 + nc0 + u * 4);
      L[nc0 + u * 4 + 0][kr] = f2bf(f.x);
      L[nc0 + u * 4 + 1][kr] = f2bf(f.y);
      L[nc0 + u * 4 + 2][kr] = f2bf(f.z);
      L[nc0 + u * 4 + 3][kr] = f2bf(f.w);
    }
  }
  __syncthreads();
  {
    const int nr = t >> 2, kc = (t & 3) * 16;
    #pragma unroll
    for (int u = 0; u < 2; ++u) {
      short8 v = *(const short8*)&L[nr][kc + u * 8];
      *(short8*)(D + (size_t)(n0 + nr) * EDIM + k0 + kc + u * 8) = v;
    }
  }
}

// ---------------------------------------------------------------------------
// bf16 MFMA GEMM: O[m][n] = A[m][:]·Bt[n][:] + bias[n]   (Bt is [N][K])
// 128x128 tile, BK=64, 4 waves (2x2), global_load_lds staging with
// XOR-chunk swizzle (chunk ^= row&7) applied on the GLOBAL source address
// (LDS dest stays linear), un-swizzled on the ds_read side.
// ---------------------------------------------------------------------------
template <typename OT, bool SCALE>
__global__ __launch_bounds__(256) void gemm_mfma(
    const short* __restrict__ A, const short* __restrict__ Bt,
    const float* __restrict__ bias, OT* __restrict__ O, int N, int K) {
  __shared__ short As[128 * 64];  // 16 KB
  __shared__ short Bs[128 * 64];  // 16 KB

  const int t = threadIdx.x;
  const int w = t >> 6, l = t & 63;
  const int m0 = blockIdx.x * 128, n0 = blockIdx.y * 128;
  const int wr = w >> 1, wc = w & 1;
  const int lr4 = l >> 4, lc = l & 15;

  f32x4 acc[4][4] = {};

  const int srow = t >> 3;                       // row within 32-row staging call
  const int schunk = (t & 7) ^ ((t >> 3) & 7);   // pre-swizzled source chunk

  for (int k0 = 0; k0 < K; k0 += 64) {
    #pragma unroll
    for (int p = 0; p < 4; ++p) {
      gload16(A + (size_t)(m0 + 32 * p + srow) * K + k0 + schunk * 8,
              As + p * 2048 + w * 512);
      gload16(Bt + (size_t)(n0 + 32 * p + srow) * K + k0 + schunk * 8,
              Bs + p * 2048 + w * 512);
    }
    __syncthreads();

    #pragma unroll
    for (int kf = 0; kf < 2; ++kf) {
      bf16x8 a[4], b[4];
      const int c = (4 * kf + lr4) ^ (l & 7);
      #pragma unroll
      for (int i = 0; i < 4; ++i)
        a[i] = *(const bf16x8*)(As + (64 * wr + 16 * i + lc) * 64 + c * 8);
      #pragma unroll
      for (int j = 0; j < 4; ++j)
        b[j] = *(const bf16x8*)(Bs + (64 * wc + 16 * j + lc) * 64 + c * 8);
      #pragma unroll
      for (int i = 0; i < 4; ++i)
        #pragma unroll
        for (int j = 0; j < 4; ++j)
          acc[i][j] = __builtin_amdgcn_mfma_f32_16x16x32_bf16(a[i], b[j], acc[i][j], 0, 0, 0);
    }
    __syncthreads();
  }

  #pragma unroll
  for (int j = 0; j < 4; ++j) {
    const int col = n0 + 64 * wc + 16 * j + lc;
    const float bv = bias[col];
    #pragma unroll
    for (int i = 0; i < 4; ++i) {
      const int rbase = m0 + 64 * wr + 16 * i + 4 * lr4;
      #pragma unroll
      for (int r = 0; r < 4; ++r) {
        float v = acc[i][j][r] + bv;
        if constexpr (SCALE) v *= 0.125f;
        if constexpr (__is_same(OT, short))
          O[(size_t)(rbase + r) * N + col] = f2bf(v);
        else
          O[(size_t)(rbase + r) * N + col] = v;
      }
    }
  }
}

// ---------------------------------------------------------------------------
// Flash attention, bf16 MFMA. Block = (q-tile 64) x (h) x (b), 4 waves.
// Wave w owns q-rows 16w..16w+15. K-tile = 64 keys.
// Ps buffer: Q at start (frags hoisted to regs), then P per tile.
// All LDS tiles [64][64] bf16 with chunk ^= (row&7) XOR swizzle.
// ---------------------------------------------------------------------------
__global__ __launch_bounds__(256) void attn_mfma(
    const short* __restrict__ Qp, const short* __restrict__ Kp,
    const short* __restrict__ Vp, const int* __restrict__ mask,
    short* __restrict__ Ctx) {
  __shared__ short Ks[64 * 64];  // [key][dim] swizzled
  __shared__ short Vt[64 * 64];  // [dim][key] swizzled
  __shared__ short Ps[64 * 64];  // Q then P: [q][*] swizzled

  const int t = threadIdx.x, w = t >> 6, l = t & 63;
  const int q0 = blockIdx.x * 64;
  const int h = blockIdx.y, b = blockIdx.z;
  const size_t hb = (size_t)b * SS * EDIM + (size_t)h * HD;
  const int lr4 = l >> 4, lc = l & 15;

  // ---- stage Q into Ps (reg->LDS, swizzled) ----
  {
    const int row = t >> 2;
    #pragma unroll
    for (int u = 0; u < 2; ++u) {
      const int cp = 2 * (t & 3) + u;
      const int c = cp ^ (row & 7);
      bf16x8 v = *(const bf16x8*)(Qp + hb + (size_t)(q0 + row) * EDIM + c * 8);
      *(bf16x8*)(Ps + row * 64 + cp * 8) = v;
    }
  }
  __syncthreads();

  bf16x8 qf[2];
  {
    const int row = 16 * w + lc;
    #pragma unroll
    for (int kf = 0; kf < 2; ++kf)
      qf[kf] = *(const bf16x8*)(Ps + row * 64 + ((4 * kf + lr4) ^ (l & 7)) * 8);
  }
  __syncthreads();

  f32x4 accO[4] = {};
  float mrow[4] = {-1e30f, -1e30f, -1e30f, -1e30f};
  float lrow[4] = {};

  const int srow = t >> 3;
  const int schunk = (t & 7) ^ ((t >> 3) & 7);

  for (int kt = 0; kt < SS / 64; ++kt) {
    const int s0 = kt * 64;
    // ---- stage K via global_load_lds (pre-swizzled source) ----
    #pragma unroll
    for (int p = 0; p < 2; ++p)
      gload16(Kp + hb + (size_t)(s0 + 32 * p + srow) * EDIM + schunk * 8,
              Ks + p * 2048 + w * 512);
    // ---- stage V transposed (reg load + scatter bf16 writes) ----
    {
      const int key = t & 63, dg = (t >> 6) * 16;
      const size_t vb = hb + (size_t)(s0 + key) * EDIM + dg;
      short8 v0 = *(const short8*)(Vp + vb);
      short8 v1 = *(const short8*)(Vp + vb + 8);
      const int kc = key >> 3, kb = key & 7;
      #pragma unroll
      for (int e = 0; e < 8; ++e) {
        const int d0 = dg + e, d1 = dg + 8 + e;
        Vt[d0 * 64 + ((kc ^ (d0 & 7)) << 3) + kb] = v0[e];
        Vt[d1 * 64 + ((kc ^ (d1 & 7)) << 3) + kb] = v1[e];
      }
    }
    __syncthreads();  // tiles ready

    // ---- S = Q K^T (per wave: 16 q-rows x 64 keys) ----
    f32x4 sacc[4] = {};
    #pragma unroll
    for (int kf = 0; kf < 2; ++kf) {
      const int c = (4 * kf + lr4) ^ (l & 7);
      #pragma unroll
      for (int nf = 0; nf < 4; ++nf) {
        bf16x8 kb8 = *(const bf16x8*)(Ks + (16 * nf + lc) * 64 + c * 8);
        sacc[nf] = __builtin_amdgcn_mfma_f32_16x16x32_bf16(qf[kf], kb8, sacc[nf], 0, 0, 0);
      }
    }

    // ---- mask + online softmax ----
    float sv[4][4];  // [nf][r]
    const int qg = q0 + 16 * w + 4 * lr4;
    #pragma unroll
    for (int nf = 0; nf < 4; ++nf)
      #pragma unroll
      for (int r = 0; r < 4; ++r) {
        float s = sacc[nf][r];
        const int mm = mask[(size_t)(qg + r) * SS + s0 + 16 * nf + lc];
        sv[nf][r] = (mm == 0) ? -1e30f : s;
      }

    float pm[4];
    #pragma unroll
    for (int r = 0; r < 4; ++r)
      pm[r] = fmaxf(fmaxf(sv[0][r], sv[1][r]), fmaxf(sv[2][r], sv[3][r]));
    #pragma unroll
    for (int off = 1; off < 16; off <<= 1)
      #pragma unroll
      for (int r = 0; r < 4; ++r)
        pm[r] = fmaxf(pm[r], __shfl_xor(pm[r], off, 64));

    float scl[4], ls[4] = {};
    #pragma unroll
    for (int r = 0; r < 4; ++r) {
      const float mn = fmaxf(mrow[r], pm[r]);
      scl[r] = __expf(mrow[r] - mn);
      mrow[r] = mn;
    }
    float pv[4][4];
    #pragma unroll
    for (int nf = 0; nf < 4; ++nf)
      #pragma unroll
      for (int r = 0; r < 4; ++r) {
        const float p = (sv[nf][r] <= -1e29f) ? 0.f : __expf(sv[nf][r] - mrow[r]);
        pv[nf][r] = p;
        ls[r] += p;
      }
    #pragma unroll
    for (int off = 1; off < 16; off <<= 1)
      #pragma unroll
      for (int r = 0; r < 4; ++r)
        ls[r] += __shfl_xor(ls[r], off, 64);
    #pragma unroll
    for (int r = 0; r < 4; ++r)
      lrow[r] = lrow[r] * scl[r] + ls[r];
    #pragma unroll
    for (int nf = 0; nf < 4; ++nf)
      #pragma unroll
      for (int r = 0; r < 4; ++r)
        accO[nf][r] *= scl[r];

    // ---- write P (bf16, swizzled) into Ps ----
    #pragma unroll
    for (int nf = 0; nf < 4; ++nf)
      #pragma unroll
      for (int r = 0; r < 4; ++r) {
        const int qq = 16 * w + 4 * lr4 + r;
        const int key = 16 * nf + lc;
        Ps[qq * 64 + (((key >> 3) ^ (qq & 7)) << 3) + (key & 7)] = f2bf(pv[nf][r]);
      }
    __syncthreads();  // P visible

    // ---- accO += P V ----
    #pragma unroll
    for (int kf = 0; kf < 2; ++kf) {
      const int c = (4 * kf + lr4) ^ (l & 7);
      bf16x8 pf = *(const bf16x8*)(Ps + (16 * w + lc) * 64 + c * 8);
      #pragma unroll
      for (int nf = 0; nf < 4; ++nf) {
        bf16x8 vb8 = *(const bf16x8*)(Vt + (16 * nf + lc) * 64 + c * 8);
        accO[nf] = __builtin_amdgcn_mfma_f32_16x16x32_bf16(pf, vb8, accO[nf], 0, 0, 0);
      }
    }
    __syncthreads();  // done reading before next stage
  }

  // ---- epilogue ----
  #pragma unroll
  for (int nf = 0; nf < 4; ++nf)
    #pragma unroll
    for (int r = 0; r < 4; ++r) {
      const int q = q0 + 16 * w + 4 * lr4 + r;
      const float v = accO[nf][r] / lrow[r];
      Ctx[hb + (size_t)q * EDIM + 16 * nf + lc] = f2bf(v);
    }
}

// ---------------------------------------------------------------------------
extern "C" void kernel_launch(void* const* d_in, const int* in_sizes, int n_in,
                              void* d_out, int out_size, void* d_ws, size_t ws_size,
                              hipStream_t stream) {
  const float* q    = (const float*)d_in[0];
  const float* k    = (const float*)d_in[1];
  const float* v    = (const float*)d_in[2];
  const int*   mask = (const int*)d_in[3];
  const float* Wqkv = (const float*)d_in[4];
  const float* bqkv = (const float*)d_in[5];
  const float* Wout = (const float*)d_in[6];
  const float* bout = (const float*)d_in[7];
  float* out = (float*)d_out;

  const size_t mat = (size_t)MTOT * EDIM;   // 4M elements
  const size_t wmat = (size_t)EDIM * EDIM;  // 1M elements
  short* Qb  = (short*)d_ws;
  short* Kb  = Qb + mat;
  short* Vb  = Kb + mat;
  short* WqT = Vb + mat;
  short* WkT = WqT + wmat;
  short* WvT = WkT + wmat;
  short* WoT = WvT + wmat;
  short* Qpj = WoT + wmat;
  short* Kpj = Qpj + mat;
  short* Vpj = Kpj + mat;
  short* Ctx = Vpj + mat;

  const int n8 = (int)(mat / 8);
  cast_bf16<<<dim3(n8 / 256), 256, 0, stream>>>(q, Qb, n8);
  cast_bf16<<<dim3(n8 / 256), 256, 0, stream>>>(k, Kb, n8);
  cast_bf16<<<dim3(n8 / 256), 256, 0, stream>>>(v, Vb, n8);

  const dim3 tg(16, 16);
  tcast<<<tg, 256, 0, stream>>>(Wqkv, 3 * EDIM, 0,        WqT);
  tcast<<<tg, 256, 0, stream>>>(Wqkv, 3 * EDIM, EDIM,     WkT);
  tcast<<<tg, 256, 0, stream>>>(Wqkv, 3 * EDIM, 2 * EDIM, WvT);
  tcast<<<tg, 256, 0, stream>>>(Wout, EDIM,     0,        WoT);

  const dim3 gg(MTOT / 128, EDIM / 128);
  gemm_mfma<short, true ><<<gg, 256, 0, stream>>>(Qb, WqT, bqkv,            Qpj, EDIM, EDIM);
  gemm_mfma<short, false><<<gg, 256, 0, stream>>>(Kb, WkT, bqkv + EDIM,     Kpj, EDIM, EDIM);
  gemm_mfma<short, false><<<gg, 256, 0, stream>>>(Vb, WvT, bqkv + 2 * EDIM, Vpj, EDIM, EDIM);

  attn_mfma<<<dim3(SS / 64, HNUM, BB), 256, 0, stream>>>(Qpj, Kpj, Vpj, mask, Ctx);

  gemm_mfma<float, false><<<gg, 256, 0, stream>>>(Ctx, WoT, bout, out, EDIM, EDIM);
}

// Round 3
// 315.277 us; speedup vs baseline: 4.1130x; 1.2298x over previous
//
#include <hip/hip_runtime.h>
#include <stdint.h>

#define EDIM 1024
#define HNUM 16
#define HD   64
#define BB   2
#define SS   2048
#define MTOT (BB * SS)

typedef __attribute__((ext_vector_type(8))) __bf16 bf16x8;
typedef __attribute__((ext_vector_type(8))) short short8;
typedef __attribute__((ext_vector_type(4))) short short4v;
typedef __attribute__((ext_vector_type(4))) float f32x4;

__device__ __forceinline__ short f2bf(float f) {
  union { float f; unsigned u; } x{f};
  unsigned r = (x.u + 0x7FFFu + ((x.u >> 16) & 1u)) >> 16;
  return (short)r;
}

__device__ __forceinline__ void gload16(const void* g, void* l) {
  __builtin_amdgcn_global_load_lds((const __attribute__((address_space(1))) void*)g,
                                   (__attribute__((address_space(3))) void*)l, 16, 0, 0);
}

// ---------------------------------------------------------------------------
// f32 -> bf16 cast, 8 elements/thread
// ---------------------------------------------------------------------------
__global__ __launch_bounds__(256) void cast_bf16(const float* __restrict__ s,
                                                 short* __restrict__ d, int n8) {
  int i = blockIdx.x * 256 + threadIdx.x;
  if (i >= n8) return;
  const float4* sp = (const float4*)s + (size_t)i * 2;
  float4 a = sp[0], b = sp[1];
  short8 r;
  r[0] = f2bf(a.x); r[1] = f2bf(a.y); r[2] = f2bf(a.z); r[3] = f2bf(a.w);
  r[4] = f2bf(b.x); r[5] = f2bf(b.y); r[6] = f2bf(b.z); r[7] = f2bf(b.w);
  *(short8*)(d + (size_t)i * 8) = r;
}

// ---------------------------------------------------------------------------
// Transpose+cast: D[n][k] = bf16(W[k][col0+n]), D is [1024][1024]
// ---------------------------------------------------------------------------
__global__ __launch_bounds__(256) void tcast(const float* __restrict__ W, int ld,
                                             int col0, short* __restrict__ D) {
  __shared__ short L[64][80];
  const int t = threadIdx.x;
  const int k0 = blockIdx.x * 64, n0 = blockIdx.y * 64;
  {
    const int kr = t >> 2, nc0 = (t & 3) * 16;
    #pragma unroll
    for (int u = 0; u < 4; ++u) {
      float4 f = *(const float4*)(W + (size_t)(k0 + kr) * ld + col0 + n0 + nc0 + u * 4);
      L[nc0 + u * 4 + 0][kr] = f2bf(f.x);
      L[nc0 + u * 4 + 1][kr] = f2bf(f.y);
      L[nc0 + u * 4 + 2][kr] = f2bf(f.z);
      L[nc0 + u * 4 + 3][kr] = f2bf(f.w);
    }
  }
  __syncthreads();
  {
    const int nr = t >> 2, kc = (t & 3) * 16;
    #pragma unroll
    for (int u = 0; u < 2; ++u) {
      short8 v = *(const short8*)&L[nr][kc + u * 8];
      *(short8*)(D + (size_t)(n0 + nr) * EDIM + k0 + kc + u * 8) = v;
    }
  }
}

// ---------------------------------------------------------------------------
// Pack mask rows into uint64 bitmasks: pm[q][kt] bit j = (mask[q][kt*64+j]!=0)
// ---------------------------------------------------------------------------
__global__ __launch_bounds__(256) void pack_mask(const int* __restrict__ mask,
                                                 unsigned long long* __restrict__ pm) {
  const int wid = (blockIdx.x * 256 + threadIdx.x) >> 6;
  const int lane = threadIdx.x & 63;
  const int q = wid >> 5, kt = wid & 31;
  const int m = mask[(size_t)q * SS + kt * 64 + lane];
  const unsigned long long b = __ballot(m != 0);
  if (lane == 0) pm[(size_t)q * 32 + kt] = b;
}

// ---------------------------------------------------------------------------
// bf16 MFMA GEMM body: O[m][n] = (A[m][:]·Bt[n][:] + bias[n]) * scale
// BM=128, BN=32*NFR, BK=64, 4 waves (2x2). global_load_lds with XOR-chunk
// source pre-swizzle, un-swizzled on ds_read.
// ---------------------------------------------------------------------------
template <int NFR, typename OT>
__device__ __forceinline__ void gemm_body(
    const short* __restrict__ A, const short* __restrict__ Bt,
    const float* __restrict__ bias, OT* __restrict__ O,
    int m0, int n0, int K, int N, float scale, short* As, short* Bs) {
  const int t = threadIdx.x;
  const int w = t >> 6, l = t & 63;
  const int wr = w >> 1, wc = w & 1;
  const int lr4 = l >> 4, lc = l & 15;

  f32x4 acc[4][NFR] = {};
  const int srow = t >> 3;
  const int schunk = (t & 7) ^ (srow & 7);

  for (int k0 = 0; k0 < K; k0 += 64) {
    #pragma unroll
    for (int p = 0; p < 4; ++p)
      gload16(A + (size_t)(m0 + 32 * p + srow) * K + k0 + schunk * 8,
              As + p * 2048 + w * 512);
    #pragma unroll
    for (int p = 0; p < NFR; ++p)
      gload16(Bt + (size_t)(n0 + 32 * p + srow) * K + k0 + schunk * 8,
              Bs + p * 2048 + w * 512);
    __syncthreads();

    #pragma unroll
    for (int kf = 0; kf < 2; ++kf) {
      const int c = ((4 * kf + lr4) ^ (lc & 7)) * 8;
      bf16x8 a[4], bfr[NFR];
      #pragma unroll
      for (int i = 0; i < 4; ++i)
        a[i] = *(const bf16x8*)(As + (64 * wr + 16 * i + lc) * 64 + c);
      #pragma unroll
      for (int j = 0; j < NFR; ++j)
        bfr[j] = *(const bf16x8*)(Bs + (16 * NFR * wc + 16 * j + lc) * 64 + c);
      #pragma unroll
      for (int i = 0; i < 4; ++i)
        #pragma unroll
        for (int j = 0; j < NFR; ++j)
          acc[i][j] = __builtin_amdgcn_mfma_f32_16x16x32_bf16(a[i], bfr[j], acc[i][j], 0, 0, 0);
    }
    __syncthreads();
  }

  #pragma unroll
  for (int j = 0; j < NFR; ++j) {
    const int col = n0 + 16 * NFR * wc + 16 * j + lc;
    const float bv = bias[col - n0 + n0];  // bias indexed by col within this output
    #pragma unroll
    for (int i = 0; i < 4; ++i) {
      const int rbase = m0 + 64 * wr + 16 * i + 4 * lr4;
      #pragma unroll
      for (int r = 0; r < 4; ++r) {
        float v = (acc[i][j][r] + bv) * scale;
        if constexpr (__is_same(OT, short))
          O[(size_t)(rbase + r) * N + col] = f2bf(v);
        else
          O[(size_t)(rbase + r) * N + col] = v;
      }
    }
  }
}

// Fused QKV projection: blockIdx.y selects {Q,K,V} x n-tile. 768 blocks.
__global__ __launch_bounds__(256) void gemm_qkv(
    const short* __restrict__ Qb, const short* __restrict__ Kb,
    const short* __restrict__ Vb, const short* __restrict__ WqT,
    const short* __restrict__ WkT, const short* __restrict__ WvT,
    const float* __restrict__ bqkv, short* __restrict__ Qpj,
    short* __restrict__ Kpj, short* __restrict__ Vpj) {
  __shared__ short As[128 * 64];
  __shared__ short Bs[128 * 64];
  const int sel = blockIdx.y >> 3;
  const int n0 = (blockIdx.y & 7) * 128;
  const short* A  = sel == 0 ? Qb : (sel == 1 ? Kb : Vb);
  const short* Bt = sel == 0 ? WqT : (sel == 1 ? WkT : WvT);
  short* O = sel == 0 ? Qpj : (sel == 1 ? Kpj : Vpj);
  const float scale = sel == 0 ? 0.125f : 1.0f;
  gemm_body<4, short>(A, Bt, bqkv + (sel << 10), O, blockIdx.x * 128, n0,
                      EDIM, EDIM, scale, As, Bs);
}

// Output projection: BN=64 -> 512 blocks (2/CU), fp32 out.
__global__ __launch_bounds__(256) void gemm_out(
    const short* __restrict__ A, const short* __restrict__ Bt,
    const float* __restrict__ bias, float* __restrict__ O) {
  __shared__ short As[128 * 64];
  __shared__ short Bs[64 * 64];
  gemm_body<2, float>(A, Bt, bias, O, blockIdx.x * 128, blockIdx.y * 64,
                      EDIM, EDIM, 1.0f, As, Bs);
}

// ---------------------------------------------------------------------------
// Flash attention, swapped-QK^T layout. Block = (64 q) x h x b, 4 waves.
// S^T = K·Q^T so each lane owns one q-row. V^T staged with key-column
// permutation rho(k)=32a+16(c>>2)+4b+(c&3) so the P^T B-fragment is the
// lane's own softmax values (no shuffles, no LDS P). Double-buffered K/V,
// one barrier per tile. Mask via packed uint64 rows.
// ---------------------------------------------------------------------------
__global__ __launch_bounds__(256) void attn_mfma(
    const short* __restrict__ Qp, const short* __restrict__ Kp,
    const short* __restrict__ Vp, const unsigned long long* __restrict__ pmask,
    short* __restrict__ Ctx) {
  __shared__ short Ks[2][64 * 64];
  __shared__ short Vt[2][64 * 64];

  const int t = threadIdx.x, w = t >> 6, l = t & 63;
  const int lr4 = l >> 4, lc = l & 15;
  const int q0 = blockIdx.x * 64;
  const int h = blockIdx.y, b = blockIdx.z;
  const size_t hb = (size_t)b * SS * EDIM + (size_t)h * HD;
  const int qrow = q0 + 16 * w + lc;  // this lane's q row

  // Q fragments straight from global (B-operand: col=q, k=d chunk)
  bf16x8 qf[2];
  #pragma unroll
  for (int kf = 0; kf < 2; ++kf)
    qf[kf] = *(const bf16x8*)(Qp + hb + (size_t)qrow * EDIM + 32 * kf + 8 * lr4);

  // staging geometry
  const int srow = t >> 3;
  const int schunk = (t & 7) ^ (srow & 7);
  const int vkey = t & 63;
  const int vdg = (t >> 6) * 16;
  // key -> permuted column: k=32a+16e+4b+f  ->  kap=32a+8b+4e+f
  const int kap = (vkey & 0x20) | ((vkey & 0xC) << 1) | ((vkey & 0x10) >> 2) | (vkey & 3);
  const int kapc = kap >> 3, kapb = kap & 7;

  // ---- prologue: stage tile 0 ----
  #pragma unroll
  for (int p = 0; p < 2; ++p)
    gload16(Kp + hb + (size_t)(32 * p + srow) * EDIM + schunk * 8,
            &Ks[0][p * 2048 + w * 512]);
  {
    short8 v0 = *(const short8*)(Vp + hb + (size_t)vkey * EDIM + vdg);
    short8 v1 = *(const short8*)(Vp + hb + (size_t)vkey * EDIM + vdg + 8);
    #pragma unroll
    for (int e = 0; e < 8; ++e) {
      const int d0 = vdg + e, d1 = vdg + 8 + e;
      Vt[0][d0 * 64 + ((kapc ^ (d0 & 7)) << 3) + kapb] = v0[e];
      Vt[0][d1 * 64 + ((kapc ^ (d1 & 7)) << 3) + kapb] = v1[e];
    }
  }
  __syncthreads();

  f32x4 accO[4] = {};
  float mrow = -1e30f, lrow = 0.f;
  const int NT = SS / 64;

  for (int kt = 0; kt < NT; ++kt) {
    const int cur = kt & 1, nxt = cur ^ 1;
    short8 nv0, nv1;
    const bool pre = (kt + 1 < NT);
    if (pre) {  // issue next-tile loads early; they land under compute
      const size_t s1 = hb + (size_t)((kt + 1) * 64) * EDIM;
      #pragma unroll
      for (int p = 0; p < 2; ++p)
        gload16(Kp + s1 + (size_t)(32 * p + srow) * EDIM + schunk * 8,
                &Ks[nxt][p * 2048 + w * 512]);
      nv0 = *(const short8*)(Vp + s1 + (size_t)vkey * EDIM + vdg);
      nv1 = *(const short8*)(Vp + s1 + (size_t)vkey * EDIM + vdg + 8);
    }
    const unsigned long long pw = pmask[(size_t)qrow * NT + kt];

    // ---- S^T = K Q^T ----
    f32x4 sacc[4] = {};
    #pragma unroll
    for (int kf = 0; kf < 2; ++kf) {
      const int c = ((4 * kf + lr4) ^ (lc & 7)) * 8;
      #pragma unroll
      for (int nf = 0; nf < 4; ++nf) {
        bf16x8 kb8 = *(const bf16x8*)(&Ks[cur][(16 * nf + lc) * 64 + c]);
        sacc[nf] = __builtin_amdgcn_mfma_f32_16x16x32_bf16(kb8, qf[kf], sacc[nf], 0, 0, 0);
      }
    }

    // ---- mask + online softmax (scalar m,l per lane) ----
    float p[4][4];
    float mt = -1e30f;
    #pragma unroll
    for (int nf = 0; nf < 4; ++nf)
      #pragma unroll
      for (int r = 0; r < 4; ++r) {
        const float s = ((pw >> (16 * nf + 4 * lr4 + r)) & 1ull) ? sacc[nf][r] : -1e30f;
        p[nf][r] = s;
        mt = fmaxf(mt, s);
      }
    mt = fmaxf(mt, __shfl_xor(mt, 16, 64));
    mt = fmaxf(mt, __shfl_xor(mt, 32, 64));
    const float mn = fmaxf(mrow, mt);
    const float scl = __expf(mrow - mn);
    mrow = mn;
    float ls = 0.f;
    #pragma unroll
    for (int nf = 0; nf < 4; ++nf)
      #pragma unroll
      for (int r = 0; r < 4; ++r) {
        const float e = (p[nf][r] <= -1e29f) ? 0.f : __expf(p[nf][r] - mn);
        p[nf][r] = e;
        ls += e;
      }
    ls += __shfl_xor(ls, 16, 64);
    ls += __shfl_xor(ls, 32, 64);
    lrow = lrow * scl + ls;
    #pragma unroll
    for (int df = 0; df < 4; ++df)
      #pragma unroll
      for (int r = 0; r < 4; ++r)
        accO[df][r] *= scl;

    // ---- P^T fragments: lane-local by construction ----
    bf16x8 pf[2];
    #pragma unroll
    for (int kf = 0; kf < 2; ++kf) {
      short8 tmp;
      #pragma unroll
      for (int j = 0; j < 8; ++j)
        tmp[j] = f2bf(p[2 * kf + (j >> 2)][j & 3]);
      pf[kf] = *(bf16x8*)&tmp;
    }

    // ---- O^T += V^T P^T ----
    #pragma unroll
    for (int kf = 0; kf < 2; ++kf) {
      const int c = ((4 * kf + lr4) ^ (lc & 7)) * 8;
      #pragma unroll
      for (int df = 0; df < 4; ++df) {
        bf16x8 va = *(const bf16x8*)(&Vt[cur][(16 * df + lc) * 64 + c]);
        accO[df] = __builtin_amdgcn_mfma_f32_16x16x32_bf16(va, pf[kf], accO[df], 0, 0, 0);
      }
    }

    if (pre) {  // late write of prefetched V into next buffer
      #pragma unroll
      for (int e = 0; e < 8; ++e) {
        const int d0 = vdg + e, d1 = vdg + 8 + e;
        Vt[nxt][d0 * 64 + ((kapc ^ (d0 & 7)) << 3) + kapb] = nv0[e];
        Vt[nxt][d1 * 64 + ((kapc ^ (d1 & 7)) << 3) + kapb] = nv1[e];
      }
    }
    __syncthreads();  // single barrier per tile
  }

  // ---- epilogue: O[q][d], d = 16df+4lr4+r (4 contiguous per df) ----
  const float inv = 1.f / lrow;
  #pragma unroll
  for (int df = 0; df < 4; ++df) {
    short4v o;
    #pragma unroll
    for (int r = 0; r < 4; ++r) o[r] = f2bf(accO[df][r] * inv);
    *(short4v*)(Ctx + hb + (size_t)qrow * EDIM + 16 * df + 4 * lr4) = o;
  }
}

// ---------------------------------------------------------------------------
extern "C" void kernel_launch(void* const* d_in, const int* in_sizes, int n_in,
                              void* d_out, int out_size, void* d_ws, size_t ws_size,
                              hipStream_t stream) {
  const float* q    = (const float*)d_in[0];
  const float* k    = (const float*)d_in[1];
  const float* v    = (const float*)d_in[2];
  const int*   mask = (const int*)d_in[3];
  const float* Wqkv = (const float*)d_in[4];
  const float* bqkv = (const float*)d_in[5];
  const float* Wout = (const float*)d_in[6];
  const float* bout = (const float*)d_in[7];
  float* out = (float*)d_out;

  const size_t mat = (size_t)MTOT * EDIM;   // 4M elements
  const size_t wmat = (size_t)EDIM * EDIM;  // 1M elements
  short* Qb  = (short*)d_ws;
  short* Kb  = Qb + mat;
  short* Vb  = Kb + mat;
  short* WqT = Vb + mat;
  short* WkT = WqT + wmat;
  short* WvT = WkT + wmat;
  short* WoT = WvT + wmat;
  short* Qpj = WoT + wmat;
  short* Kpj = Qpj + mat;
  short* Vpj = Kpj + mat;
  short* Ctx = Vpj + mat;
  unsigned long long* pm = (unsigned long long*)(Ctx + mat);  // 512 KB

  const int n8 = (int)(mat / 8);
  cast_bf16<<<dim3(n8 / 256), 256, 0, stream>>>(q, Qb, n8);
  cast_bf16<<<dim3(n8 / 256), 256, 0, stream>>>(k, Kb, n8);
  cast_bf16<<<dim3(n8 / 256), 256, 0, stream>>>(v, Vb, n8);

  const dim3 tg(16, 16);
  tcast<<<tg, 256, 0, stream>>>(Wqkv, 3 * EDIM, 0,        WqT);
  tcast<<<tg, 256, 0, stream>>>(Wqkv, 3 * EDIM, EDIM,     WkT);
  tcast<<<tg, 256, 0, stream>>>(Wqkv, 3 * EDIM, 2 * EDIM, WvT);
  tcast<<<tg, 256, 0, stream>>>(Wout, EDIM,     0,        WoT);

  pack_mask<<<dim3((SS * 32 * 64) / 256), 256, 0, stream>>>(mask, pm);

  gemm_qkv<<<dim3(MTOT / 128, 24), 256, 0, stream>>>(Qb, Kb, Vb, WqT, WkT, WvT,
                                                     bqkv, Qpj, Kpj, Vpj);

  attn_mfma<<<dim3(SS / 64, HNUM, BB), 256, 0, stream>>>(Qpj, Kpj, Vpj, pm, Ctx);

  gemm_out<<<dim3(MTOT / 128, EDIM / 64), 256, 0, stream>>>(Ctx, WoT, bout, out);
}

// Round 4
// 267.768 us; speedup vs baseline: 4.8428x; 1.1774x over previous
//
#include <hip/hip_runtime.h>
#include <stdint.h>

#define EDIM 1024
#define HNUM 16
#define HD   64
#define BB   2
#define SS   2048
#define MTOT (BB * SS)

typedef __attribute__((ext_vector_type(8))) __bf16 bf16x8;
typedef __attribute__((ext_vector_type(8))) short short8;
typedef __attribute__((ext_vector_type(4))) short short4v;
typedef __attribute__((ext_vector_type(4))) float f32x4;

__device__ __forceinline__ short bfbits(float f) {
  __bf16 h = (__bf16)f;
  return __builtin_bit_cast(short, h);
}

__device__ __forceinline__ void gload16(const void* g, void* l) {
  __builtin_amdgcn_global_load_lds((const __attribute__((address_space(1))) void*)g,
                                   (__attribute__((address_space(3))) void*)l, 16, 0, 0);
}

// key -> permuted V^T column within a 64-key tile (preserves low 2 bits)
__device__ __forceinline__ int kap_perm(int k) {
  return (k & 0x20) | ((k & 0xC) << 1) | ((k & 0x10) >> 2) | (k & 3);
}

// ---------------------------------------------------------------------------
// Fused prep: [0,6144) f32->bf16 casts of q/k/v; [6144,7168) weight
// transpose+cast; [7168,23552) mask bit-packing.
// ---------------------------------------------------------------------------
__global__ __launch_bounds__(256) void prep(
    const float* __restrict__ q, const float* __restrict__ k,
    const float* __restrict__ v, const float* __restrict__ Wqkv,
    const float* __restrict__ Wout, const int* __restrict__ mask,
    short* __restrict__ Qb, short* __restrict__ Kb, short* __restrict__ Vb,
    short* __restrict__ WqT, short* __restrict__ WkT, short* __restrict__ WvT,
    short* __restrict__ WoT, unsigned long long* __restrict__ pm) {
  __shared__ short L[64][80];
  const int bid = blockIdx.x, t = threadIdx.x;

  if (bid < 6144) {  // ---- casts ----
    const int which = bid >> 11;
    const int i = (bid & 2047) * 256 + t;
    const float* s = which == 0 ? q : (which == 1 ? k : v);
    short* d = which == 0 ? Qb : (which == 1 ? Kb : Vb);
    const float4* sp = (const float4*)s + (size_t)i * 2;
    float4 a = sp[0], b = sp[1];
    short8 r;
    r[0] = bfbits(a.x); r[1] = bfbits(a.y); r[2] = bfbits(a.z); r[3] = bfbits(a.w);
    r[4] = bfbits(b.x); r[5] = bfbits(b.y); r[6] = bfbits(b.z); r[7] = bfbits(b.w);
    *(short8*)(d + (size_t)i * 8) = r;
  } else if (bid < 7168) {  // ---- weight transpose+cast ----
    const int tb = bid - 6144;
    const int which = tb >> 8;
    const int k0 = ((tb >> 4) & 15) * 64, n0 = (tb & 15) * 64;
    const float* W = which == 3 ? Wout : Wqkv;
    const int ld = which == 3 ? EDIM : 3 * EDIM;
    const int col0 = which == 3 ? 0 : which * EDIM;
    short* D = which == 0 ? WqT : (which == 1 ? WkT : (which == 2 ? WvT : WoT));
    {
      const int kr = t >> 2, nc0 = (t & 3) * 16;
      #pragma unroll
      for (int u = 0; u < 4; ++u) {
        float4 f = *(const float4*)(W + (size_t)(k0 + kr) * ld + col0 + n0 + nc0 + u * 4);
        L[nc0 + u * 4 + 0][kr] = bfbits(f.x);
        L[nc0 + u * 4 + 1][kr] = bfbits(f.y);
        L[nc0 + u * 4 + 2][kr] = bfbits(f.z);
        L[nc0 + u * 4 + 3][kr] = bfbits(f.w);
      }
    }
    __syncthreads();
    {
      const int nr = t >> 2, kc = (t & 3) * 16;
      #pragma unroll
      for (int u = 0; u < 2; ++u) {
        short8 vv = *(const short8*)&L[nr][kc + u * 8];
        *(short8*)(D + (size_t)(n0 + nr) * EDIM + k0 + kc + u * 8) = vv;
      }
    }
  } else {  // ---- mask packing ----
    const int wid = (bid - 7168) * 4 + (t >> 6);
    const int lane = t & 63;
    const int qq = wid >> 5, kt = wid & 31;
    const int m = mask[(size_t)qq * SS + kt * 64 + lane];
    const unsigned long long b = __ballot(m != 0);
    if (lane == 0) pm[(size_t)qq * 32 + kt] = b;
  }
}

// ---------------------------------------------------------------------------
// bf16 MFMA GEMM body. BM=128, BN=32*NFR, BK=64, 4 waves (2x2).
// MODE 0: bf16 row-major out; MODE 1: f32 row-major out;
// MODE 2: bf16 V^T out [b][h][64][SS] with kap column permutation.
// ---------------------------------------------------------------------------
template <int NFR, int MODE, typename OT>
__device__ __forceinline__ void gemm_body(
    const short* __restrict__ A, const short* __restrict__ Bt,
    const float* __restrict__ bias, OT* __restrict__ O,
    int m0, int n0, int K, int N, float scale, short* As, short* Bs) {
  const int t = threadIdx.x;
  const int w = t >> 6, l = t & 63;
  const int wr = w >> 1, wc = w & 1;
  const int lr4 = l >> 4, lc = l & 15;

  f32x4 acc[4][NFR] = {};
  const int srow = t >> 3;
  const int schunk = (t & 7) ^ (srow & 7);

  for (int k0 = 0; k0 < K; k0 += 64) {
    #pragma unroll
    for (int p = 0; p < 4; ++p)
      gload16(A + (size_t)(m0 + 32 * p + srow) * K + k0 + schunk * 8,
              As + p * 2048 + w * 512);
    #pragma unroll
    for (int p = 0; p < NFR; ++p)
      gload16(Bt + (size_t)(n0 + 32 * p + srow) * K + k0 + schunk * 8,
              Bs + p * 2048 + w * 512);
    __syncthreads();

    #pragma unroll
    for (int kf = 0; kf < 2; ++kf) {
      const int c = ((4 * kf + lr4) ^ (lc & 7)) * 8;
      bf16x8 a[4], bfr[NFR];
      #pragma unroll
      for (int i = 0; i < 4; ++i)
        a[i] = *(const bf16x8*)(As + (64 * wr + 16 * i + lc) * 64 + c);
      #pragma unroll
      for (int j = 0; j < NFR; ++j)
        bfr[j] = *(const bf16x8*)(Bs + (16 * NFR * wc + 16 * j + lc) * 64 + c);
      #pragma unroll
      for (int i = 0; i < 4; ++i)
        #pragma unroll
        for (int j = 0; j < NFR; ++j)
          acc[i][j] = __builtin_amdgcn_mfma_f32_16x16x32_bf16(a[i], bfr[j], acc[i][j], 0, 0, 0);
    }
    __syncthreads();
  }

  #pragma unroll
  for (int j = 0; j < NFR; ++j) {
    const int col = n0 + 16 * NFR * wc + 16 * j + lc;
    const float bv = bias[col];
    #pragma unroll
    for (int i = 0; i < 4; ++i) {
      const int rbase = m0 + 64 * wr + 16 * i + 4 * lr4;
      if constexpr (MODE == 2) {
        const int bidx = rbase >> 11, s = rbase & 2047;
        const int hh = col >> 6, dd = col & 63;
        short4v o;
        #pragma unroll
        for (int r = 0; r < 4; ++r) o[r] = bfbits((acc[i][j][r] + bv) * scale);
        *(short4v*)((short*)O + (((size_t)bidx * HNUM + hh) * 64 + dd) * SS +
                    (s & ~63) + kap_perm(s & 63)) = o;
      } else {
        #pragma unroll
        for (int r = 0; r < 4; ++r) {
          float vv = (acc[i][j][r] + bv) * scale;
          if constexpr (MODE == 0)
            ((short*)O)[(size_t)(rbase + r) * N + col] = bfbits(vv);
          else
            ((float*)O)[(size_t)(rbase + r) * N + col] = vv;
        }
      }
    }
  }
}

// Fused QKV projection: blockIdx.y selects {Q,K,V} x n-tile. 768 blocks.
// Q is pre-scaled by (1/sqrt(D)) * log2(e) so attention works in exp2 domain.
// V is stored transposed+permuted for direct global_load_lds in attention.
__global__ __launch_bounds__(256) void gemm_qkv(
    const short* __restrict__ Qb, const short* __restrict__ Kb,
    const short* __restrict__ Vb, const short* __restrict__ WqT,
    const short* __restrict__ WkT, const short* __restrict__ WvT,
    const float* __restrict__ bqkv, short* __restrict__ Qpj,
    short* __restrict__ Kpj, short* __restrict__ VT) {
  __shared__ short As[128 * 64];
  __shared__ short Bs[128 * 64];
  const int sel = blockIdx.y >> 3;
  const int n0 = (blockIdx.y & 7) * 128;
  const int m0 = blockIdx.x * 128;
  if (sel == 0)
    gemm_body<4, 0, short>(Qb, WqT, bqkv, Qpj, m0, n0, EDIM, EDIM,
                           0.125f * 1.44269504089f, As, Bs);
  else if (sel == 1)
    gemm_body<4, 0, short>(Kb, WkT, bqkv + EDIM, Kpj, m0, n0, EDIM, EDIM,
                           1.0f, As, Bs);
  else
    gemm_body<4, 2, short>(Vb, WvT, bqkv + 2 * EDIM, VT, m0, n0, EDIM, EDIM,
                           1.0f, As, Bs);
}

// Output projection: BN=64 -> 512 blocks, fp32 out.
__global__ __launch_bounds__(256) void gemm_out(
    const short* __restrict__ A, const short* __restrict__ Bt,
    const float* __restrict__ bias, float* __restrict__ O) {
  __shared__ short As[128 * 64];
  __shared__ short Bs[64 * 64];
  gemm_body<2, 1, float>(A, Bt, bias, O, blockIdx.x * 128, blockIdx.y * 64,
                         EDIM, EDIM, 1.0f, As, Bs);
}

// ---------------------------------------------------------------------------
// Flash attention, swapped-QK^T, exp2 domain, defer-max, all-gload staging.
// Block = (64 q) x h x b, 4 waves; wave w owns q-rows 16w..16w+15, each lane
// one q-row. K [key][d] and V^T [d][kap(key)] double-buffered in LDS via
// global_load_lds with XOR-chunk source pre-swizzle. One barrier per tile.
// ---------------------------------------------------------------------------
__global__ __launch_bounds__(256) void attn_mfma(
    const short* __restrict__ Qp, const short* __restrict__ Kp,
    const short* __restrict__ VT, const unsigned long long* __restrict__ pmask,
    short* __restrict__ Ctx) {
  __shared__ short Ks[2][64 * 64];
  __shared__ short Vt[2][64 * 64];

  const int t = threadIdx.x, w = t >> 6, l = t & 63;
  const int lr4 = l >> 4, lc = l & 15;
  const int q0 = blockIdx.x * 64;
  const int h = blockIdx.y, b = blockIdx.z;
  const size_t hb = (size_t)b * SS * EDIM + (size_t)h * HD;
  const size_t hv = ((size_t)b * HNUM + h) * 64 * SS;  // V^T base
  const int qrow = q0 + 16 * w + lc;

  // Q fragments straight from global (B-operand: col=q, k=d chunk)
  bf16x8 qf[2];
  #pragma unroll
  for (int kf = 0; kf < 2; ++kf)
    qf[kf] = *(const bf16x8*)(Qp + hb + (size_t)qrow * EDIM + 32 * kf + 8 * lr4);

  const int srow = t >> 3;
  const int schunk = (t & 7) ^ (srow & 7);

  // ---- prologue: stage tile 0 ----
  #pragma unroll
  for (int p = 0; p < 2; ++p) {
    gload16(Kp + hb + (size_t)(32 * p + srow) * EDIM + schunk * 8,
            &Ks[0][p * 2048 + w * 512]);
    gload16(VT + hv + (size_t)(32 * p + srow) * SS + schunk * 8,
            &Vt[0][p * 2048 + w * 512]);
  }
  __syncthreads();

  f32x4 accO[4] = {};
  float mrow = -1e30f, lrow = 0.f;
  const int NT = SS / 64;

  for (int kt = 0; kt < NT; ++kt) {
    const int cur = kt & 1, nxt = cur ^ 1;
    // mask word first (so its wait doesn't drain the prefetch gloads)
    const unsigned long long pw = pmask[(size_t)qrow * NT + kt];
    if (kt + 1 < NT) {  // async prefetch of next tile
      const size_t sK = hb + (size_t)((kt + 1) * 64) * EDIM;
      const size_t sV = hv + (size_t)((kt + 1) * 64);
      #pragma unroll
      for (int p = 0; p < 2; ++p) {
        gload16(Kp + sK + (size_t)(32 * p + srow) * EDIM + schunk * 8,
                &Ks[nxt][p * 2048 + w * 512]);
        gload16(VT + sV + (size_t)(32 * p + srow) * SS + schunk * 8,
                &Vt[nxt][p * 2048 + w * 512]);
      }
    }

    // ---- S^T = K Q^T (log2 domain) ----
    f32x4 sacc[4] = {};
    #pragma unroll
    for (int kf = 0; kf < 2; ++kf) {
      const int c = ((4 * kf + lr4) ^ (lc & 7)) * 8;
      #pragma unroll
      for (int nf = 0; nf < 4; ++nf) {
        bf16x8 kb8 = *(const bf16x8*)(&Ks[cur][(16 * nf + lc) * 64 + c]);
        sacc[nf] = __builtin_amdgcn_mfma_f32_16x16x32_bf16(kb8, qf[kf], sacc[nf], 0, 0, 0);
      }
    }

    // ---- online softmax: unmasked running max + defer-max ----
    float mt = -1e30f;
    #pragma unroll
    for (int nf = 0; nf < 4; ++nf)
      #pragma unroll
      for (int r = 0; r < 4; ++r)
        mt = fmaxf(mt, sacc[nf][r]);
    mt = fmaxf(mt, __shfl_xor(mt, 16, 64));
    mt = fmaxf(mt, __shfl_xor(mt, 32, 64));

    if (__any(mt > mrow + 7.0f)) {  // rescale path (rare after warmup)
      const float mn = fmaxf(mrow, mt);
      const float scl = exp2f(mrow - mn);
      mrow = mn;
      lrow *= scl;
      #pragma unroll
      for (int df = 0; df < 4; ++df)
        #pragma unroll
        for (int r = 0; r < 4; ++r)
          accO[df][r] *= scl;
    }

    // ---- P = mask ? exp2(s - m) : 0 ; lane-local P^T fragments ----
    float ls = 0.f;
    bf16x8 pf[2];
    #pragma unroll
    for (int nf = 0; nf < 4; ++nf) {
      const unsigned nib = (unsigned)(pw >> (16 * nf + 4 * lr4)) & 15u;
      #pragma unroll
      for (int r = 0; r < 4; ++r) {
        const float e = exp2f(sacc[nf][r] - mrow);
        const float p = (nib >> r) & 1u ? e : 0.f;
        ls += p;
        pf[nf >> 1][4 * (nf & 1) + r] = (__bf16)p;
      }
    }
    ls += __shfl_xor(ls, 16, 64);
    ls += __shfl_xor(ls, 32, 64);
    lrow += ls;

    // ---- O^T += V^T P^T ----
    #pragma unroll
    for (int kf = 0; kf < 2; ++kf) {
      const int c = ((4 * kf + lr4) ^ (lc & 7)) * 8;
      #pragma unroll
      for (int df = 0; df < 4; ++df) {
        bf16x8 va = *(const bf16x8*)(&Vt[cur][(16 * df + lc) * 64 + c]);
        accO[df] = __builtin_amdgcn_mfma_f32_16x16x32_bf16(va, pf[kf], accO[df], 0, 0, 0);
      }
    }
    __syncthreads();  // drains prefetch gloads; next tile ready
  }

  // ---- epilogue ----
  const float inv = 1.f / lrow;
  #pragma unroll
  for (int df = 0; df < 4; ++df) {
    short4v o;
    #pragma unroll
    for (int r = 0; r < 4; ++r) o[r] = bfbits(accO[df][r] * inv);
    *(short4v*)(Ctx + hb + (size_t)qrow * EDIM + 16 * df + 4 * lr4) = o;
  }
}

// ---------------------------------------------------------------------------
extern "C" void kernel_launch(void* const* d_in, const int* in_sizes, int n_in,
                              void* d_out, int out_size, void* d_ws, size_t ws_size,
                              hipStream_t stream) {
  const float* q    = (const float*)d_in[0];
  const float* k    = (const float*)d_in[1];
  const float* v    = (const float*)d_in[2];
  const int*   mask = (const int*)d_in[3];
  const float* Wqkv = (const float*)d_in[4];
  const float* bqkv = (const float*)d_in[5];
  const float* Wout = (const float*)d_in[6];
  const float* bout = (const float*)d_in[7];
  float* out = (float*)d_out;

  const size_t mat = (size_t)MTOT * EDIM;   // 4M elements
  const size_t wmat = (size_t)EDIM * EDIM;  // 1M elements
  short* Qb  = (short*)d_ws;
  short* Kb  = Qb + mat;
  short* Vb  = Kb + mat;
  short* WqT = Vb + mat;
  short* WkT = WqT + wmat;
  short* WvT = WkT + wmat;
  short* WoT = WvT + wmat;
  short* Qpj = WoT + wmat;
  short* Kpj = Qpj + mat;
  short* VT  = Kpj + mat;   // [B][H][64][SS] transposed+permuted V
  short* Ctx = VT + mat;
  unsigned long long* pm = (unsigned long long*)(Ctx + mat);  // 512 KB

  prep<<<dim3(23552), 256, 0, stream>>>(q, k, v, Wqkv, Wout, mask,
                                        Qb, Kb, Vb, WqT, WkT, WvT, WoT, pm);

  gemm_qkv<<<dim3(MTOT / 128, 24), 256, 0, stream>>>(Qb, Kb, Vb, WqT, WkT, WvT,
                                                     bqkv, Qpj, Kpj, VT);

  attn_mfma<<<dim3(SS / 64, HNUM, BB), 256, 0, stream>>>(Qpj, Kpj, VT, pm, Ctx);

  gemm_out<<<dim3(MTOT / 128, EDIM / 64), 256, 0, stream>>>(Ctx, WoT, bout, out);
}